// Round 9
// baseline (144.707 us; speedup 1.0000x reference)
//
#include <hip/hip_runtime.h>

constexpr int Bb = 8;
constexpr int Nn = 2048;
constexpr int Cc = 64;
constexpr int CAPS = 192;

typedef __attribute__((ext_vector_type(4))) float f32x4;
typedef __attribute__((ext_vector_type(16))) float f32x16;
typedef __attribute__((ext_vector_type(8))) short bf16x8;
typedef __attribute__((ext_vector_type(4))) unsigned u32x4;

__device__ inline unsigned short f2bf(float f){
  unsigned u = __builtin_bit_cast(unsigned, f);
  unsigned r = (u + 0x7FFFu + ((u>>16)&1u)) >> 16;
  return (unsigned short)r;
}
__device__ inline float bf2f(unsigned short h){
  unsigned u = ((unsigned)h)<<16; return __builtin_bit_cast(float,u);
}
__device__ inline unsigned pk2(float a, float b){
  return (unsigned)f2bf(a) | ((unsigned)f2bf(b)<<16);
}

// frag-major layouts: 16B chunk index -> element offset (in shorts)
// Q/K: element (row j|m, c): s=row>>5, q=c>>4, l=(row&31)+32*((c>>3)&1), short c&7
__device__ inline size_t qk_chunk(int b, int s, int q, int l){
  return ((((size_t)b*64 + s)*4 + q)*64 + l)*8;
}
// xz: element (c, m): mq=m>>4, cb=c>>5, l=(c&31)+32*((m>>3)&1), short m&7
__device__ inline size_t xz_chunk(int b, int mq, int cb, int l){
  return ((((size_t)b*128 + mq)*2 + cb)*64 + l)*8;
}

#define MFMA32(a,b,c) __builtin_amdgcn_mfma_f32_32x32x16_bf16(a,b,c,0,0,0)

// ===== mega pre-kernel: prep(QK hi/lo frag-major + xt + xsum partials) | extract | WvT =====
__global__ __launch_bounds__(256) void mega_k(
    const float* __restrict__ x, const float* __restrict__ A,
    const float* __restrict__ Wq, const float* __restrict__ Wk,
    const float* __restrict__ Tw, const float* __restrict__ Wv,
    unsigned short* __restrict__ Qhi, unsigned short* __restrict__ Qlo,
    unsigned short* __restrict__ Khi, unsigned short* __restrict__ Klo,
    float* __restrict__ xt, float* __restrict__ Xp,
    float* __restrict__ r_, float* __restrict__ diagA, int* __restrict__ cnt,
    int* __restrict__ idx, float* __restrict__ val,
    float* __restrict__ WvT){
  __shared__ __attribute__((aligned(16))) char smem[65792];
  int blk = blockIdx.x; int t = threadIdx.x;

  if(blk < 256){
    // ---------------- prep ----------------
    float* wql = (float*)smem;           // 4096 f
    float* wkl = wql + 4096;
    float* twl = wkl + 4096;
    float (*xr)[64] = (float(*)[64])(twl + 4096); // [64][64]
    float* xsl = (float*)(xr + 64);      // 64 f
    #pragma unroll
    for(int i=0;i<4;i++){
      *(f32x4*)&wql[i*1024+t*4] = *(const f32x4*)&Wq[i*1024+t*4];
      *(f32x4*)&wkl[i*1024+t*4] = *(const f32x4*)&Wk[i*1024+t*4];
      *(f32x4*)&twl[i*1024+t*4] = *(const f32x4*)&Tw[i*1024+t*4];
    }
    if(t<64) xsl[t]=0.f;
    long long row0 = (long long)blk*64;
    int r = t>>4, q = t&15, c0 = q*4;
    #pragma unroll
    for(int i=0;i<4;i++){
      int row = i*16 + r;
      *(f32x4*)&xr[row][c0] = *(const f32x4*)&x[(row0+row)*Cc + c0];
    }
    __syncthreads();
    f32x4 aq[4], ak[4], at4[4];
    #pragma unroll
    for(int g=0;g<4;g++){ aq[g]=(f32x4){0,0,0,0}; ak[g]=(f32x4){0,0,0,0}; at4[g]=(f32x4){0,0,0,0}; }
    for(int kk=0;kk<64;kk++){
      f32x4 wq4 = *(const f32x4*)&wql[kk*64+c0];
      f32x4 wk4 = *(const f32x4*)&wkl[kk*64+c0];
      f32x4 wt4 = *(const f32x4*)&twl[kk*64+c0];
      #pragma unroll
      for(int g=0;g<4;g++){
        float xv = xr[g*16+r][kk];
        aq[g] += xv*wq4; ak[g] += xv*wk4; at4[g] += xv*wt4;
      }
    }
    float xsp[4] = {0.f,0.f,0.f,0.f};
    int q2 = c0>>4, hb = (c0>>3)&1, cs = c0&7;
    #pragma unroll
    for(int g=0;g<4;g++){
      #pragma unroll
      for(int d=0;d<4;d++) xsp[d] += xr[g*16+r][c0+d];
      long long rg = row0 + g*16 + r;
      unsigned long long hq=0,lq=0,hk=0,lk=0;
      #pragma unroll
      for(int d=0;d<4;d++){
        float v = aq[g][d];
        unsigned short h = f2bf(v); unsigned short lo2 = f2bf(v - bf2f(h));
        hq |= (unsigned long long)h << (16*d); lq |= (unsigned long long)lo2 << (16*d);
        v = ak[g][d];
        h = f2bf(v); lo2 = f2bf(v - bf2f(h));
        hk |= (unsigned long long)h << (16*d); lk |= (unsigned long long)lo2 << (16*d);
      }
      int b2 = (int)(rg>>11); int s2 = ((int)rg>>5)&63;
      int l2 = ((int)rg&31) + 32*hb;
      size_t off = qk_chunk(b2, s2, q2, l2) + cs;
      *(unsigned long long*)&Qhi[off] = hq;
      *(unsigned long long*)&Qlo[off] = lq;
      *(unsigned long long*)&Khi[off] = hk;
      *(unsigned long long*)&Klo[off] = lk;
      *(f32x4*)&xt[rg*Cc + c0] = at4[g];
    }
    __syncthreads();
    #pragma unroll
    for(int d=0;d<4;d++) atomicAdd(&xsl[c0+d], xsp[d]);
    __syncthreads();
    if(t<64) Xp[blk*64+t] = xsl[t];
  } else if(blk < 768){
    // ---------------- extract ----------------
    int n = (blk-256)*4 + (t>>6); int l = t&63;
    const float* row = A + (size_t)n*Nn;
    float mn = 1e30f;
    for(int j=l;j<Nn;j+=64) mn = fminf(mn, row[j]);
    #pragma unroll
    for(int off=32;off>=1;off>>=1) mn = fminf(mn, __shfl_xor(mn,off));
    float thr = mn*1.3f;
    int bse=0;
    for(int j0=0;j0<Nn;j0+=64){
      float v = row[j0+l];
      bool f = v>thr;
      unsigned long long m = __ballot(f);
      int pos = __popcll(m & ((1ull<<l)-1ull));
      if(f && bse+pos<CAPS){ idx[n*CAPS+bse+pos]=j0+l; val[n*CAPS+bse+pos]=v-mn; }
      bse += __popcll(m);
    }
    if(l==0){ r_[n]=mn; diagA[n]=row[n]; cnt[n] = bse<CAPS? bse : CAPS; }
  } else {
    // ---------------- WvT ----------------
    float (*tile)[65] = (float(*)[65])smem;
    int n0 = (blk-768)*64;
    for(int i=0;i<16;i++){
      int cc = i*4 + (t>>6); int nn2 = t&63;
      tile[cc][nn2] = Wv[(size_t)cc*Nn + n0 + nn2];
    }
    __syncthreads();
    for(int i=0;i<16;i++){
      int nn2 = i*4 + (t>>6); int cc = t&63;
      WvT[(size_t)(n0+nn2)*Cc + cc] = tile[cc][nn2];
    }
  }
}

// ===== zpass: Zp[jq][b][m] = sum_{j in quarter} exp(Q·K); grid (b,mt,jq), no atomics =====
__global__ __launch_bounds__(256,4) void zpass_k(
    const unsigned short* __restrict__ Qhi, const unsigned short* __restrict__ Qlo,
    const unsigned short* __restrict__ Khi, const unsigned short* __restrict__ Klo,
    float* __restrict__ Zp){
  __shared__ float Zl[32];
  int id = blockIdx.x;
  int b = id&7; int mt = (id>>3)&63; int jq = id>>9;   // 8 x 64 x 4 = 2048 blocks
  int t = threadIdx.x, w = t>>6, l = t&63;
  if(t<32) Zl[t]=0.f;
  __syncthreads();
  bf16x8 Kh[4], Kl4[4];
  #pragma unroll
  for(int q=0;q<4;q++){
    Kh[q]  = *(const bf16x8*)(Khi + qk_chunk(b, mt, q, l));
    Kl4[q] = *(const bf16x8*)(Klo + qk_chunk(b, mt, q, l));
  }
  float zacc = 0.f;
  #pragma unroll
  for(int jt=0; jt<4; jt++){
    int s = jq*16 + w*4 + jt;
    bf16x8 Qh4[4], Ql4[4];
    #pragma unroll
    for(int q=0;q<4;q++){
      Qh4[q] = *(const bf16x8*)(Qhi + qk_chunk(b, s, q, l));
      Ql4[q] = *(const bf16x8*)(Qlo + qk_chunk(b, s, q, l));
    }
    f32x16 sa, sb;
    #pragma unroll
    for(int r=0;r<16;r++){ sa[r]=0.f; sb[r]=0.f; }
    #pragma unroll
    for(int q=0;q<4;q++){
      sa = MFMA32(Qh4[q], Kh[q],  sa);   // hi·hi chain
      sb = MFMA32(Ql4[q], Kh[q],  sb);   // lo·hi + hi·lo chain
      sb = MFMA32(Qh4[q], Kl4[q], sb);
    }
    float p = 0.f;
    #pragma unroll
    for(int r=0;r<16;r++) p += __expf(sa[r]+sb[r]);
    zacc += p;
  }
  zacc += __shfl_down(zacc, 32);
  if(l<32) atomicAdd(&Zl[l], zacc);
  __syncthreads();
  if(t<32) Zp[((size_t)(jq*8 + b))*Nn + mt*32 + t] = Zl[t];
}

// ===== xzt: xzf (frag-major) = bf16(x[b,m,c] / sum_jq Zp) =====
__global__ __launch_bounds__(256) void xzt_k(const float* __restrict__ x,
    const float* __restrict__ Zp, unsigned short* __restrict__ xzf){
  __shared__ float tile[64][65];
  __shared__ float izl[64];
  int id = blockIdx.x; int b = id&7; int mt = id>>3;  // 32 m-tiles of 64
  int m0 = mt*64; int t = threadIdx.x;
  for(int i=0;i<16;i++){
    int mm = i*4 + (t>>6); int cc = t&63;
    tile[mm][cc] = x[((size_t)b*Nn + m0+mm)*Cc + cc];
  }
  if(t<64){
    float z = 0.f;
    #pragma unroll
    for(int jq=0;jq<4;jq++) z += Zp[((size_t)(jq*8 + b))*Nn + m0 + t];
    izl[t] = 1.0f/z;
  }
  __syncthreads();
  #pragma unroll
  for(int i=0;i<2;i++){
    int k2 = i*256 + t; int mg = k2>>6; int c = k2&63;
    int mloc = mg*8;
    unsigned u0 = pk2(tile[mloc+0][c]*izl[mloc+0], tile[mloc+1][c]*izl[mloc+1]);
    unsigned u1 = pk2(tile[mloc+2][c]*izl[mloc+2], tile[mloc+3][c]*izl[mloc+3]);
    unsigned u2 = pk2(tile[mloc+4][c]*izl[mloc+4], tile[mloc+5][c]*izl[mloc+5]);
    unsigned u3 = pk2(tile[mloc+6][c]*izl[mloc+6], tile[mloc+7][c]*izl[mloc+7]);
    u32x4 uu = {u0,u1,u2,u3};
    int mq = (m0 + mloc)>>4; int cb = c>>5; int l2 = (c&31) + 32*(mg&1);
    *(u32x4*)(xzf + xz_chunk(b, mq, cb, l2)) = uu;
  }
}

// ===== fused: Pp[mh][b,j,c] = sum_{m in half} bf16(exp(K·Q))*xz; grid (b,js,mh) =====
__global__ __launch_bounds__(256,3) void fused_k(
    const unsigned short* __restrict__ Qhi, const unsigned short* __restrict__ Qlo,
    const unsigned short* __restrict__ Khi, const unsigned short* __restrict__ Klo,
    const unsigned short* __restrict__ xzf, float* __restrict__ Pp){
  __shared__ float plds[32*64];
  int id = blockIdx.x;
  int b = id&7; int js = (id>>3)&63; int mh = id>>9;   // 8 x 64 x 2 = 1024 blocks
  int t = threadIdx.x, w = t>>6, l = t&63, lr = l&31, hh = l>>5;
  #pragma unroll
  for(int i=0;i<8;i++) plds[i*256+t]=0.f;
  __syncthreads();
  // hoisted Q B-frags (swapped: Q is the B operand, col = j)
  bf16x8 Qh4[4], Ql4[4];
  #pragma unroll
  for(int q=0;q<4;q++){
    Qh4[q] = *(const bf16x8*)(Qhi + qk_chunk(b, js, q, l));
    Ql4[q] = *(const bf16x8*)(Qlo + qk_chunk(b, js, q, l));
  }
  f32x16 pa0, pa1;
  #pragma unroll
  for(int r=0;r<16;r++){ pa0[r]=0.f; pa1[r]=0.f; }
  for(int mt=0; mt<8; mt++){
    int s = mh*32 + w*8 + mt;          // m-sub of 32
    bf16x8 Kh4[4], Kl4[4];
    #pragma unroll
    for(int q=0;q<4;q++){
      Kh4[q] = *(const bf16x8*)(Khi + qk_chunk(b, s, q, l));
      Kl4[q] = *(const bf16x8*)(Klo + qk_chunk(b, s, q, l));
    }
    int mq = s*2;
    bf16x8 b00 = *(const bf16x8*)(xzf + xz_chunk(b, mq,   0, l));
    bf16x8 b01 = *(const bf16x8*)(xzf + xz_chunk(b, mq+1, 0, l));
    bf16x8 b10 = *(const bf16x8*)(xzf + xz_chunk(b, mq,   1, l));
    bf16x8 b11 = *(const bf16x8*)(xzf + xz_chunk(b, mq+1, 1, l));
    f32x16 sa, sb;
    #pragma unroll
    for(int r=0;r<16;r++){ sa[r]=0.f; sb[r]=0.f; }
    #pragma unroll
    for(int q=0;q<4;q++){
      sa = MFMA32(Kh4[q], Qh4[q], sa);   // hi·hi chain
      sb = MFMA32(Kl4[q], Qh4[q], sb);   // lo·hi + hi·lo chain
      sb = MFMA32(Kh4[q], Ql4[q], sb);
    }
    // E = bf16(exp(S)); relayout C-frag -> A-frags via permlane32_swap (T12)
    unsigned wd0,wd1,wd2,wd3,wd4,wd5,wd6,wd7;
    {
      unsigned x0 = pk2(__expf(sa[0]+sb[0]),   __expf(sa[1]+sb[1]));
      unsigned x1 = pk2(__expf(sa[2]+sb[2]),   __expf(sa[3]+sb[3]));
      unsigned y0 = pk2(__expf(sa[4]+sb[4]),   __expf(sa[5]+sb[5]));
      unsigned y1 = pk2(__expf(sa[6]+sb[6]),   __expf(sa[7]+sb[7]));
      asm("v_permlane32_swap_b32 %0, %1" : "+v"(x0), "+v"(y0));
      asm("v_permlane32_swap_b32 %0, %1" : "+v"(x1), "+v"(y1));
      wd0=x0; wd1=x1; wd2=y0; wd3=y1;
      unsigned x2 = pk2(__expf(sa[8]+sb[8]),   __expf(sa[9]+sb[9]));
      unsigned x3 = pk2(__expf(sa[10]+sb[10]), __expf(sa[11]+sb[11]));
      unsigned y2 = pk2(__expf(sa[12]+sb[12]), __expf(sa[13]+sb[13]));
      unsigned y3 = pk2(__expf(sa[14]+sb[14]), __expf(sa[15]+sb[15]));
      asm("v_permlane32_swap_b32 %0, %1" : "+v"(x2), "+v"(y2));
      asm("v_permlane32_swap_b32 %0, %1" : "+v"(x3), "+v"(y3));
      wd4=x2; wd5=x3; wd6=y2; wd7=y3;
    }
    u32x4 u1 = {wd0,wd1,wd2,wd3};
    u32x4 u2 = {wd4,wd5,wd6,wd7};
    bf16x8 f1 = __builtin_bit_cast(bf16x8, u1);   // E rows j, k = m 0..15 of tile
    bf16x8 f2 = __builtin_bit_cast(bf16x8, u2);   // E rows j, k = m 16..31
    pa0 = MFMA32(f1, b00, pa0);
    pa0 = MFMA32(f2, b01, pa0);
    pa1 = MFMA32(f1, b10, pa1);
    pa1 = MFMA32(f2, b11, pa1);
  }
  // reduce m-slices across 4 waves in LDS (conflict-free: lanes consecutive)
  #pragma unroll
  for(int r=0;r<16;r++){
    int jr = (r&3) + 8*(r>>2) + 4*hh;
    atomicAdd(&plds[jr*64 + lr],      pa0[r]);
    atomicAdd(&plds[jr*64 + 32 + lr], pa1[r]);
  }
  __syncthreads();
  {
    float* Pb = Pp + (size_t)mh*Bb*Nn*Cc + ((size_t)b*Nn + js*32)*Cc;
    int j = t>>3, c0 = (t&7)*8;
    *(f32x4*)(Pb + (size_t)j*Cc + c0)     = *(const f32x4*)&plds[j*64 + c0];
    *(f32x4*)(Pb + (size_t)j*Cc + c0 + 4) = *(const f32x4*)&plds[j*64 + c0 + 4];
  }
}

// ---------------- final: dy_diag + elementwise combine (sums 2 P-halves) ----------------
__global__ __launch_bounds__(256) void final_k(const float* __restrict__ x,
    const float* __restrict__ xt, const float* __restrict__ Pp,
    const float* __restrict__ WvT, const float* __restrict__ Xp,
    const float* __restrict__ r_, const float* __restrict__ diagA,
    const int* __restrict__ cnt, const int* __restrict__ idx,
    const float* __restrict__ val, const float* __restrict__ tb,
    const float* __restrict__ alp, const float* __restrict__ bet,
    float* __restrict__ out){
  int t=threadIdx.x; int l=t&63;
  int bn = blockIdx.x*4 + (t>>6);
  int b = bn>>11, n = bn&2047;
  float wv = WvT[n*Cc+l];
  float xs = 0.f;
  const float* xpb = Xp + (size_t)b*32*Cc;
  #pragma unroll 8
  for(int p=0;p<32;p++) xs += xpb[p*Cc + l];
  float tacc = r_[n]*xs;
  int cn = cnt[n];
  const float* Pb0 = Pp + (size_t)b*Nn*Cc;
  const float* Pb1 = Pp + (size_t)Bb*Nn*Cc + (size_t)b*Nn*Cc;
  const int* ix = idx + n*CAPS;
  const float* vl = val + n*CAPS;
  for(int k=0;k<cn;k++){
    size_t ro = (size_t)ix[k]*Cc + l;
    tacc += vl[k] * (Pb0[ro] + Pb1[ro]);
  }
  float d = wv*tacc;
  #pragma unroll
  for(int off=32;off>=1;off>>=1) d += __shfl_xor(d,off);
  size_t g = (size_t)bn*Cc + l;
  float o = alp[0]*diagA[n]*x[g] + bet[0]*(d*xt[g] + tb[l]);
  out[g] = fmaxf(o,0.f);
}

extern "C" void kernel_launch(void* const* d_in, const int* in_sizes, int n_in,
                              void* d_out, int out_size, void* d_ws, size_t ws_size,
                              hipStream_t stream){
  const float* x  = (const float*)d_in[0];
  const float* A  = (const float*)d_in[1];
  const float* Wq = (const float*)d_in[2];
  const float* Wk = (const float*)d_in[3];
  const float* Wv = (const float*)d_in[4];
  const float* Tw = (const float*)d_in[5];
  const float* tb = (const float*)d_in[6];
  const float* alp= (const float*)d_in[7];
  const float* bet= (const float*)d_in[8];
  float* out = (float*)d_out;

  char* base = (char*)d_ws; size_t off=0;
  auto al=[&](size_t sz)->void*{ void* q = base+off; off=(off+sz+255)&~(size_t)255; return q; };
  unsigned short* Qhi=(unsigned short*)al((size_t)Bb*Nn*Cc*2);
  unsigned short* Qlo=(unsigned short*)al((size_t)Bb*Nn*Cc*2);
  unsigned short* Khi=(unsigned short*)al((size_t)Bb*Nn*Cc*2);
  unsigned short* Klo=(unsigned short*)al((size_t)Bb*Nn*Cc*2);
  float* xt  =(float*)al((size_t)Bb*Nn*Cc*4);
  float* Pp  =(float*)al((size_t)2*Bb*Nn*Cc*4);  // two m-halves, fully written by fused_k
  float* Zp  =(float*)al((size_t)4*Bb*Nn*4);     // four j-quarters, fully written by zpass_k
  float* Xp  =(float*)al((size_t)256*Cc*4);
  float* WvT =(float*)al((size_t)Nn*Cc*4);
  float* r_  =(float*)al((size_t)Nn*4);
  float* dgA =(float*)al((size_t)Nn*4);
  int*   cnt =(int*)al((size_t)Nn*4);
  int*   idx =(int*)al((size_t)Nn*CAPS*4);
  float* val =(float*)al((size_t)Nn*CAPS*4);
  unsigned short* xzf=(unsigned short*)al((size_t)Bb*Cc*Nn*2);
  (void)ws_size;

  mega_k<<<800, 256, 0, stream>>>(x, A, Wq, Wk, Tw, Wv,
      Qhi, Qlo, Khi, Klo, xt, Xp, r_, dgA, cnt, idx, val, WvT);
  zpass_k<<<2048, 256, 0, stream>>>(Qhi,Qlo,Khi,Klo,Zp);
  xzt_k<<<256, 256, 0, stream>>>(x,Zp,xzf);
  fused_k<<<1024, 256, 0, stream>>>(Qhi,Qlo,Khi,Klo,xzf,Pp);
  final_k<<<Bb*Nn/4, 256, 0, stream>>>(x,xt,Pp,WvT,Xp,r_,dgA,cnt,idx,val,tb,alp,bet,out);
}

// Round 10
// 110.468 us; speedup vs baseline: 1.3099x; 1.3099x over previous
//
#include <hip/hip_runtime.h>

constexpr int Bb = 8;
constexpr int Nn = 2048;
constexpr int Cc = 64;
constexpr int CAPS = 192;

typedef __attribute__((ext_vector_type(4))) float f32x4;
typedef __attribute__((ext_vector_type(16))) float f32x16;
typedef __attribute__((ext_vector_type(8))) short bf16x8;
typedef __attribute__((ext_vector_type(4))) unsigned u32x4;

__device__ inline unsigned short f2bf(float f){
  unsigned u = __builtin_bit_cast(unsigned, f);
  unsigned r = (u + 0x7FFFu + ((u>>16)&1u)) >> 16;
  return (unsigned short)r;
}
__device__ inline float bf2f(unsigned short h){
  unsigned u = ((unsigned)h)<<16; return __builtin_bit_cast(float,u);
}
__device__ inline unsigned pk2(float a, float b){
  return (unsigned)f2bf(a) | ((unsigned)f2bf(b)<<16);
}

typedef __attribute__((address_space(1))) unsigned GU32;
typedef __attribute__((address_space(3))) unsigned LU32;
__device__ inline void load_lds16(const void* g, void* l){
  __builtin_amdgcn_global_load_lds((const GU32*)g, (LU32*)l, 16, 0, 0);
}

// frag-major layouts: 16B chunk index -> element offset (in shorts)
// Q/K: element (row j|m, c): s=row>>5, q=c>>4, l=(row&31)+32*((c>>3)&1), short c&7
__device__ inline size_t qk_chunk(int b, int s, int q, int l){
  return ((((size_t)b*64 + s)*4 + q)*64 + l)*8;
}
// xz: element (c, m): mq=m>>4, cb=c>>5, l=(c&31)+32*((m>>3)&1), short m&7
__device__ inline size_t xz_chunk(int b, int mq, int cb, int l){
  return ((((size_t)b*128 + mq)*2 + cb)*64 + l)*8;
}

#define MFMA32(a,b,c) __builtin_amdgcn_mfma_f32_32x32x16_bf16(a,b,c,0,0,0)

// ===== mega pre-kernel: prep(QK hi/lo frag-major + xt + xsum partials) | extract | WvT =====
__global__ __launch_bounds__(256) void mega_k(
    const float* __restrict__ x, const float* __restrict__ A,
    const float* __restrict__ Wq, const float* __restrict__ Wk,
    const float* __restrict__ Tw, const float* __restrict__ Wv,
    unsigned short* __restrict__ Qhi, unsigned short* __restrict__ Qlo,
    unsigned short* __restrict__ Khi, unsigned short* __restrict__ Klo,
    float* __restrict__ xt, float* __restrict__ Xp,
    float* __restrict__ r_, float* __restrict__ diagA, int* __restrict__ cnt,
    int* __restrict__ idx, float* __restrict__ val,
    float* __restrict__ WvT){
  __shared__ __attribute__((aligned(16))) char smem[65792];
  int blk = blockIdx.x; int t = threadIdx.x;

  if(blk < 256){
    // ---------------- prep ----------------
    float* wql = (float*)smem;           // 4096 f
    float* wkl = wql + 4096;
    float* twl = wkl + 4096;
    float (*xr)[64] = (float(*)[64])(twl + 4096); // [64][64]
    float* xsl = (float*)(xr + 64);      // 64 f
    #pragma unroll
    for(int i=0;i<4;i++){
      *(f32x4*)&wql[i*1024+t*4] = *(const f32x4*)&Wq[i*1024+t*4];
      *(f32x4*)&wkl[i*1024+t*4] = *(const f32x4*)&Wk[i*1024+t*4];
      *(f32x4*)&twl[i*1024+t*4] = *(const f32x4*)&Tw[i*1024+t*4];
    }
    if(t<64) xsl[t]=0.f;
    long long row0 = (long long)blk*64;
    int r = t>>4, q = t&15, c0 = q*4;
    #pragma unroll
    for(int i=0;i<4;i++){
      int row = i*16 + r;
      *(f32x4*)&xr[row][c0] = *(const f32x4*)&x[(row0+row)*Cc + c0];
    }
    __syncthreads();
    f32x4 aq[4], ak[4], at4[4];
    #pragma unroll
    for(int g=0;g<4;g++){ aq[g]=(f32x4){0,0,0,0}; ak[g]=(f32x4){0,0,0,0}; at4[g]=(f32x4){0,0,0,0}; }
    for(int kk=0;kk<64;kk++){
      f32x4 wq4 = *(const f32x4*)&wql[kk*64+c0];
      f32x4 wk4 = *(const f32x4*)&wkl[kk*64+c0];
      f32x4 wt4 = *(const f32x4*)&twl[kk*64+c0];
      #pragma unroll
      for(int g=0;g<4;g++){
        float xv = xr[g*16+r][kk];
        aq[g] += xv*wq4; ak[g] += xv*wk4; at4[g] += xv*wt4;
      }
    }
    float xsp[4] = {0.f,0.f,0.f,0.f};
    int q2 = c0>>4, hb = (c0>>3)&1, cs = c0&7;
    #pragma unroll
    for(int g=0;g<4;g++){
      #pragma unroll
      for(int d=0;d<4;d++) xsp[d] += xr[g*16+r][c0+d];
      long long rg = row0 + g*16 + r;
      unsigned long long hq=0,lq=0,hk=0,lk=0;
      #pragma unroll
      for(int d=0;d<4;d++){
        float v = aq[g][d];
        unsigned short h = f2bf(v); unsigned short lo2 = f2bf(v - bf2f(h));
        hq |= (unsigned long long)h << (16*d); lq |= (unsigned long long)lo2 << (16*d);
        v = ak[g][d];
        h = f2bf(v); lo2 = f2bf(v - bf2f(h));
        hk |= (unsigned long long)h << (16*d); lk |= (unsigned long long)lo2 << (16*d);
      }
      int b2 = (int)(rg>>11); int s2 = ((int)rg>>5)&63;
      int l2 = ((int)rg&31) + 32*hb;
      size_t off = qk_chunk(b2, s2, q2, l2) + cs;
      *(unsigned long long*)&Qhi[off] = hq;
      *(unsigned long long*)&Qlo[off] = lq;
      *(unsigned long long*)&Khi[off] = hk;
      *(unsigned long long*)&Klo[off] = lk;
      *(f32x4*)&xt[rg*Cc + c0] = at4[g];
    }
    __syncthreads();
    #pragma unroll
    for(int d=0;d<4;d++) atomicAdd(&xsl[c0+d], xsp[d]);
    __syncthreads();
    if(t<64) Xp[blk*64+t] = xsl[t];
  } else if(blk < 768){
    // ---------------- extract ----------------
    int n = (blk-256)*4 + (t>>6); int l = t&63;
    const float* row = A + (size_t)n*Nn;
    float mn = 1e30f;
    for(int j=l;j<Nn;j+=64) mn = fminf(mn, row[j]);
    #pragma unroll
    for(int off=32;off>=1;off>>=1) mn = fminf(mn, __shfl_xor(mn,off));
    float thr = mn*1.3f;
    int bse=0;
    for(int j0=0;j0<Nn;j0+=64){
      float v = row[j0+l];
      bool f = v>thr;
      unsigned long long m = __ballot(f);
      int pos = __popcll(m & ((1ull<<l)-1ull));
      if(f && bse+pos<CAPS){ idx[n*CAPS+bse+pos]=j0+l; val[n*CAPS+bse+pos]=v-mn; }
      bse += __popcll(m);
    }
    if(l==0){ r_[n]=mn; diagA[n]=row[n]; cnt[n] = bse<CAPS? bse : CAPS; }
  } else {
    // ---------------- WvT ----------------
    float (*tile)[65] = (float(*)[65])smem;
    int n0 = (blk-768)*64;
    for(int i=0;i<16;i++){
      int cc = i*4 + (t>>6); int nn2 = t&63;
      tile[cc][nn2] = Wv[(size_t)cc*Nn + n0 + nn2];
    }
    __syncthreads();
    for(int i=0;i<16;i++){
      int nn2 = i*4 + (t>>6); int cc = t&63;
      WvT[(size_t)(n0+nn2)*Cc + cc] = tile[cc][nn2];
    }
  }
}

// ===== zpass: Zp[jq][b][m]; block = 4 waves (wave owns m-tile), Q streamed via LDS dbuf =====
__global__ __launch_bounds__(256,2) void zpass_k(
    const unsigned short* __restrict__ Qhi, const unsigned short* __restrict__ Qlo,
    const unsigned short* __restrict__ Khi, const unsigned short* __restrict__ Klo,
    float* __restrict__ Zp){
  __shared__ uint4 stg[2][512];   // 2 x 8KB: [0:256)=Qhi s-tile, [256:512)=Qlo
  int id = blockIdx.x;
  int b = id&7; int mg = (id>>3)&15; int jq = id>>7;   // 8 x 16 x 4 = 512 blocks
  int t = threadIdx.x, w = t>>6, l = t&63;
  int mt = mg*4 + w;
  // K frags in regs (per wave)
  bf16x8 Kh[4], Kl4[4];
  #pragma unroll
  for(int q=0;q<4;q++){
    Kh[q]  = *(const bf16x8*)(Khi + qk_chunk(b, mt, q, l));
    Kl4[q] = *(const bf16x8*)(Klo + qk_chunk(b, mt, q, l));
  }
  char* wbase0 = (char*)&stg[0][0] + (t>>6)*1024;
  char* wbase1 = (char*)&stg[1][0] + (t>>6)*1024;
  // prologue stage s = jq*16
  {
    int s = jq*16;
    load_lds16(Qhi + qk_chunk(b,s,0,0) + t*8, wbase0);
    load_lds16(Qlo + qk_chunk(b,s,0,0) + t*8, wbase0 + 4096);
  }
  __syncthreads();
  float zacc = 0.f;
  for(int it=0; it<16; it++){
    int buf = it&1;
    if(it+1<16){
      int s = jq*16 + it + 1;
      char* wb = buf? wbase0 : wbase1;
      load_lds16(Qhi + qk_chunk(b,s,0,0) + t*8, wb);
      load_lds16(Qlo + qk_chunk(b,s,0,0) + t*8, wb + 4096);
    }
    f32x16 sa, sb;
    #pragma unroll
    for(int r=0;r<16;r++){ sa[r]=0.f; sb[r]=0.f; }
    #pragma unroll
    for(int q=0;q<4;q++){
      bf16x8 Qh4 = *(const bf16x8*)&stg[buf][q*64 + l];
      bf16x8 Ql4 = *(const bf16x8*)&stg[buf][256 + q*64 + l];
      sa = MFMA32(Qh4, Kh[q],  sa);   // hi·hi chain
      sb = MFMA32(Ql4, Kh[q],  sb);   // lo·hi + hi·lo chain
      sb = MFMA32(Qh4, Kl4[q], sb);
    }
    float p = 0.f;
    #pragma unroll
    for(int r=0;r<16;r++) p += __expf(sa[r]+sb[r]);
    zacc += p;
    __syncthreads();   // drains prefetch (vmcnt) + ds; next buf ready
  }
  zacc += __shfl_down(zacc, 32);
  if(l<32) Zp[((size_t)(jq*8 + b))*Nn + mt*32 + l] = zacc;
}

// ===== xzt: xzf (frag-major) = bf16(x[b,m,c] / sum_jq Zp) =====
__global__ __launch_bounds__(256) void xzt_k(const float* __restrict__ x,
    const float* __restrict__ Zp, unsigned short* __restrict__ xzf){
  __shared__ float tile[64][65];
  __shared__ float izl[64];
  int id = blockIdx.x; int b = id&7; int mt = id>>3;  // 32 m-tiles of 64
  int m0 = mt*64; int t = threadIdx.x;
  for(int i=0;i<16;i++){
    int mm = i*4 + (t>>6); int cc = t&63;
    tile[mm][cc] = x[((size_t)b*Nn + m0+mm)*Cc + cc];
  }
  if(t<64){
    float z = 0.f;
    #pragma unroll
    for(int jq=0;jq<4;jq++) z += Zp[((size_t)(jq*8 + b))*Nn + m0 + t];
    izl[t] = 1.0f/z;
  }
  __syncthreads();
  #pragma unroll
  for(int i=0;i<2;i++){
    int k2 = i*256 + t; int mg = k2>>6; int c = k2&63;
    int mloc = mg*8;
    unsigned u0 = pk2(tile[mloc+0][c]*izl[mloc+0], tile[mloc+1][c]*izl[mloc+1]);
    unsigned u1 = pk2(tile[mloc+2][c]*izl[mloc+2], tile[mloc+3][c]*izl[mloc+3]);
    unsigned u2 = pk2(tile[mloc+4][c]*izl[mloc+4], tile[mloc+5][c]*izl[mloc+5]);
    unsigned u3 = pk2(tile[mloc+6][c]*izl[mloc+6], tile[mloc+7][c]*izl[mloc+7]);
    u32x4 uu = {u0,u1,u2,u3};
    int mq = (m0 + mloc)>>4; int cb = c>>5; int l2 = (c&31) + 32*(mg&1);
    *(u32x4*)(xzf + xz_chunk(b, mq, cb, l2)) = uu;
  }
}

// ===== fused: Pp[mq][b,j,c]; block = 4 waves (wave owns j-subtile), K+xz streamed via LDS =====
__global__ __launch_bounds__(256,2) void fused_k(
    const unsigned short* __restrict__ Qhi, const unsigned short* __restrict__ Qlo,
    const unsigned short* __restrict__ Khi, const unsigned short* __restrict__ Klo,
    const unsigned short* __restrict__ xzf, float* __restrict__ Pp){
  __shared__ uint4 stg[2][768];  // 2 x 12KB: [0:256)=Khi, [256:512)=Klo, [512:768)=xz
  int id = blockIdx.x;
  int b = id&7; int jb = (id>>3)&15; int mq4 = id>>7;   // 8 x 16 x 4 = 512 blocks
  int t = threadIdx.x, w = t>>6, l = t&63, lr = l&31, hh = l>>5;
  int js = jb*4 + w;
  // hoisted Q B-frags in regs (swapped: Q is the B operand, col = j)
  bf16x8 Qh4[4], Ql4[4];
  #pragma unroll
  for(int q=0;q<4;q++){
    Qh4[q] = *(const bf16x8*)(Qhi + qk_chunk(b, js, q, l));
    Ql4[q] = *(const bf16x8*)(Qlo + qk_chunk(b, js, q, l));
  }
  char* wbase0 = (char*)&stg[0][0] + (t>>6)*1024;
  char* wbase1 = (char*)&stg[1][0] + (t>>6)*1024;
  // prologue stage s = mq4*16
  {
    int s = mq4*16;
    load_lds16(Khi + qk_chunk(b,s,0,0) + t*8, wbase0);
    load_lds16(Klo + qk_chunk(b,s,0,0) + t*8, wbase0 + 4096);
    load_lds16(xzf + xz_chunk(b,2*s,0,0) + t*8, wbase0 + 8192);
  }
  __syncthreads();
  f32x16 pa0, pa1;
  #pragma unroll
  for(int r=0;r<16;r++){ pa0[r]=0.f; pa1[r]=0.f; }
  for(int it=0; it<16; it++){
    int buf = it&1;
    if(it+1<16){
      int s = mq4*16 + it + 1;
      char* wb = buf? wbase0 : wbase1;
      load_lds16(Khi + qk_chunk(b,s,0,0) + t*8, wb);
      load_lds16(Klo + qk_chunk(b,s,0,0) + t*8, wb + 4096);
      load_lds16(xzf + xz_chunk(b,2*s,0,0) + t*8, wb + 8192);
    }
    f32x16 sa, sb;
    #pragma unroll
    for(int r=0;r<16;r++){ sa[r]=0.f; sb[r]=0.f; }
    #pragma unroll
    for(int q=0;q<4;q++){
      bf16x8 Kh4 = *(const bf16x8*)&stg[buf][q*64 + l];
      bf16x8 Kl4 = *(const bf16x8*)&stg[buf][256 + q*64 + l];
      sa = MFMA32(Kh4, Qh4[q], sa);   // hi·hi chain
      sb = MFMA32(Kl4, Qh4[q], sb);   // lo·hi + hi·lo chain
      sb = MFMA32(Kh4, Ql4[q], sb);
    }
    bf16x8 b00 = *(const bf16x8*)&stg[buf][512 + l];        // (mq,  cb0)
    bf16x8 b10 = *(const bf16x8*)&stg[buf][512 + 64 + l];   // (mq,  cb1)
    bf16x8 b01 = *(const bf16x8*)&stg[buf][512 + 128 + l];  // (mq+1,cb0)
    bf16x8 b11 = *(const bf16x8*)&stg[buf][512 + 192 + l];  // (mq+1,cb1)
    // E = bf16(exp(S)); relayout C-frag -> A-frags via permlane32_swap (T12)
    unsigned wd0,wd1,wd2,wd3,wd4,wd5,wd6,wd7;
    {
      unsigned x0 = pk2(__expf(sa[0]+sb[0]),   __expf(sa[1]+sb[1]));
      unsigned x1 = pk2(__expf(sa[2]+sb[2]),   __expf(sa[3]+sb[3]));
      unsigned y0 = pk2(__expf(sa[4]+sb[4]),   __expf(sa[5]+sb[5]));
      unsigned y1 = pk2(__expf(sa[6]+sb[6]),   __expf(sa[7]+sb[7]));
      asm("v_permlane32_swap_b32 %0, %1" : "+v"(x0), "+v"(y0));
      asm("v_permlane32_swap_b32 %0, %1" : "+v"(x1), "+v"(y1));
      wd0=x0; wd1=x1; wd2=y0; wd3=y1;
      unsigned x2 = pk2(__expf(sa[8]+sb[8]),   __expf(sa[9]+sb[9]));
      unsigned x3 = pk2(__expf(sa[10]+sb[10]), __expf(sa[11]+sb[11]));
      unsigned y2 = pk2(__expf(sa[12]+sb[12]), __expf(sa[13]+sb[13]));
      unsigned y3 = pk2(__expf(sa[14]+sb[14]), __expf(sa[15]+sb[15]));
      asm("v_permlane32_swap_b32 %0, %1" : "+v"(x2), "+v"(y2));
      asm("v_permlane32_swap_b32 %0, %1" : "+v"(x3), "+v"(y3));
      wd4=x2; wd5=x3; wd6=y2; wd7=y3;
    }
    u32x4 u1 = {wd0,wd1,wd2,wd3};
    u32x4 u2 = {wd4,wd5,wd6,wd7};
    bf16x8 f1 = __builtin_bit_cast(bf16x8, u1);   // E rows j, k = m 0..15 of tile
    bf16x8 f2 = __builtin_bit_cast(bf16x8, u2);   // E rows j, k = m 16..31
    pa0 = MFMA32(f1, b00, pa0);
    pa0 = MFMA32(f2, b01, pa0);
    pa1 = MFMA32(f1, b10, pa1);
    pa1 = MFMA32(f2, b11, pa1);
    __syncthreads();   // drains prefetch; next buf ready
  }
  // epilogue: direct store (once per block; wave owns complete rows for this m-quarter)
  float* Pb = Pp + ((size_t)(mq4*8 + b)*Nn + js*32)*Cc;
  #pragma unroll
  for(int r=0;r<16;r++){
    int jr = (r&3) + 8*(r>>2) + 4*hh;
    Pb[(size_t)jr*Cc + lr]      = pa0[r];
    Pb[(size_t)jr*Cc + 32 + lr] = pa1[r];
  }
}

// ---------------- final: dy_diag + elementwise combine (sums 4 P-quarters) ----------------
__global__ __launch_bounds__(256) void final_k(const float* __restrict__ x,
    const float* __restrict__ xt, const float* __restrict__ Pp,
    const float* __restrict__ WvT, const float* __restrict__ Xp,
    const float* __restrict__ r_, const float* __restrict__ diagA,
    const int* __restrict__ cnt, const int* __restrict__ idx,
    const float* __restrict__ val, const float* __restrict__ tb,
    const float* __restrict__ alp, const float* __restrict__ bet,
    float* __restrict__ out){
  int t=threadIdx.x; int l=t&63;
  int bn = blockIdx.x*4 + (t>>6);
  int b = bn>>11, n = bn&2047;
  float wv = WvT[n*Cc+l];
  float xs = 0.f;
  const float* xpb = Xp + (size_t)b*32*Cc;
  #pragma unroll 8
  for(int p=0;p<32;p++) xs += xpb[p*Cc + l];
  float tacc = r_[n]*xs;
  int cn = cnt[n];
  const float* Pb0 = Pp + (size_t)(0*8+b)*Nn*Cc;
  const float* Pb1 = Pp + (size_t)(1*8+b)*Nn*Cc;
  const float* Pb2 = Pp + (size_t)(2*8+b)*Nn*Cc;
  const float* Pb3 = Pp + (size_t)(3*8+b)*Nn*Cc;
  const int* ix = idx + n*CAPS;
  const float* vl = val + n*CAPS;
  for(int k=0;k<cn;k++){
    size_t ro = (size_t)ix[k]*Cc + l;
    tacc += vl[k] * ((Pb0[ro] + Pb1[ro]) + (Pb2[ro] + Pb3[ro]));
  }
  float d = wv*tacc;
  #pragma unroll
  for(int off=32;off>=1;off>>=1) d += __shfl_xor(d,off);
  size_t g = (size_t)bn*Cc + l;
  float o = alp[0]*diagA[n]*x[g] + bet[0]*(d*xt[g] + tb[l]);
  out[g] = fmaxf(o,0.f);
}

extern "C" void kernel_launch(void* const* d_in, const int* in_sizes, int n_in,
                              void* d_out, int out_size, void* d_ws, size_t ws_size,
                              hipStream_t stream){
  const float* x  = (const float*)d_in[0];
  const float* A  = (const float*)d_in[1];
  const float* Wq = (const float*)d_in[2];
  const float* Wk = (const float*)d_in[3];
  const float* Wv = (const float*)d_in[4];
  const float* Tw = (const float*)d_in[5];
  const float* tb = (const float*)d_in[6];
  const float* alp= (const float*)d_in[7];
  const float* bet= (const float*)d_in[8];
  float* out = (float*)d_out;

  char* base = (char*)d_ws; size_t off=0;
  auto al=[&](size_t sz)->void*{ void* q = base+off; off=(off+sz+255)&~(size_t)255; return q; };
  unsigned short* Qhi=(unsigned short*)al((size_t)Bb*Nn*Cc*2);
  unsigned short* Qlo=(unsigned short*)al((size_t)Bb*Nn*Cc*2);
  unsigned short* Khi=(unsigned short*)al((size_t)Bb*Nn*Cc*2);
  unsigned short* Klo=(unsigned short*)al((size_t)Bb*Nn*Cc*2);
  float* xt  =(float*)al((size_t)Bb*Nn*Cc*4);
  float* Pp  =(float*)al((size_t)4*Bb*Nn*Cc*4);  // four m-quarters, fully written by fused_k
  float* Zp  =(float*)al((size_t)4*Bb*Nn*4);     // four j-quarters, fully written by zpass_k
  float* Xp  =(float*)al((size_t)256*Cc*4);
  float* WvT =(float*)al((size_t)Nn*Cc*4);
  float* r_  =(float*)al((size_t)Nn*4);
  float* dgA =(float*)al((size_t)Nn*4);
  int*   cnt =(int*)al((size_t)Nn*4);
  int*   idx =(int*)al((size_t)Nn*CAPS*4);
  float* val =(float*)al((size_t)Nn*CAPS*4);
  unsigned short* xzf=(unsigned short*)al((size_t)Bb*Cc*Nn*2);
  (void)ws_size;

  mega_k<<<800, 256, 0, stream>>>(x, A, Wq, Wk, Tw, Wv,
      Qhi, Qlo, Khi, Klo, xt, Xp, r_, dgA, cnt, idx, val, WvT);
  zpass_k<<<512, 256, 0, stream>>>(Qhi,Qlo,Khi,Klo,Zp);
  xzt_k<<<256, 256, 0, stream>>>(x,Zp,xzf);
  fused_k<<<512, 256, 0, stream>>>(Qhi,Qlo,Khi,Klo,xzf,Pp);
  final_k<<<Bb*Nn/4, 256, 0, stream>>>(x,xt,Pp,WvT,Xp,r_,dgA,cnt,idx,val,tb,alp,bet,out);
}

// Round 11
// 107.358 us; speedup vs baseline: 1.3479x; 1.0290x over previous
//
#include <hip/hip_runtime.h>

constexpr int Bb = 8;
constexpr int Nn = 2048;
constexpr int Cc = 64;
constexpr int CAPS = 192;

typedef __attribute__((ext_vector_type(4))) float f32x4;
typedef __attribute__((ext_vector_type(16))) float f32x16;
typedef __attribute__((ext_vector_type(8))) short bf16x8;
typedef __attribute__((ext_vector_type(4))) unsigned u32x4;

__device__ inline unsigned short f2bf(float f){
  unsigned u = __builtin_bit_cast(unsigned, f);
  unsigned r = (u + 0x7FFFu + ((u>>16)&1u)) >> 16;
  return (unsigned short)r;
}
__device__ inline float bf2f(unsigned short h){
  unsigned u = ((unsigned)h)<<16; return __builtin_bit_cast(float,u);
}
__device__ inline unsigned pk2(float a, float b){
  return (unsigned)f2bf(a) | ((unsigned)f2bf(b)<<16);
}

typedef __attribute__((address_space(1))) unsigned GU32;
typedef __attribute__((address_space(3))) unsigned LU32;
__device__ inline void load_lds16(const void* g, void* l){
  __builtin_amdgcn_global_load_lds((const GU32*)g, (LU32*)l, 16, 0, 0);
}

// frag-major layouts: 16B chunk index -> element offset (in shorts)
// Q/K: element (row j|m, c): s=row>>5, q=c>>4, l=(row&31)+32*((c>>3)&1), short c&7
__device__ inline size_t qk_chunk(int b, int s, int q, int l){
  return ((((size_t)b*64 + s)*4 + q)*64 + l)*8;
}
// xz: element (c, m): mq=m>>4, cb=c>>5, l=(c&31)+32*((m>>3)&1), short m&7
__device__ inline size_t xz_chunk(int b, int mq, int cb, int l){
  return ((((size_t)b*128 + mq)*2 + cb)*64 + l)*8;
}

#define MFMA32(a,b,c) __builtin_amdgcn_mfma_f32_32x32x16_bf16(a,b,c,0,0,0)

// ===== mega pre-kernel: prep(QK hi/lo frag-major + xt + xsum partials) | extract | WvT =====
__global__ __launch_bounds__(256) void mega_k(
    const float* __restrict__ x, const float* __restrict__ A,
    const float* __restrict__ Wq, const float* __restrict__ Wk,
    const float* __restrict__ Tw, const float* __restrict__ Wv,
    unsigned short* __restrict__ Qhi, unsigned short* __restrict__ Qlo,
    unsigned short* __restrict__ Khi, unsigned short* __restrict__ Klo,
    float* __restrict__ xt, float* __restrict__ Xp,
    float* __restrict__ r_, float* __restrict__ diagA, int* __restrict__ cnt,
    int* __restrict__ idx, float* __restrict__ val,
    float* __restrict__ WvT){
  __shared__ __attribute__((aligned(16))) char smem[65792];
  int blk = blockIdx.x; int t = threadIdx.x;

  if(blk < 256){
    // ---------------- prep ----------------
    float* wql = (float*)smem;           // 4096 f
    float* wkl = wql + 4096;
    float* twl = wkl + 4096;
    float (*xr)[64] = (float(*)[64])(twl + 4096); // [64][64]
    float* xsl = (float*)(xr + 64);      // 64 f
    #pragma unroll
    for(int i=0;i<4;i++){
      *(f32x4*)&wql[i*1024+t*4] = *(const f32x4*)&Wq[i*1024+t*4];
      *(f32x4*)&wkl[i*1024+t*4] = *(const f32x4*)&Wk[i*1024+t*4];
      *(f32x4*)&twl[i*1024+t*4] = *(const f32x4*)&Tw[i*1024+t*4];
    }
    if(t<64) xsl[t]=0.f;
    long long row0 = (long long)blk*64;
    int r = t>>4, q = t&15, c0 = q*4;
    #pragma unroll
    for(int i=0;i<4;i++){
      int row = i*16 + r;
      *(f32x4*)&xr[row][c0] = *(const f32x4*)&x[(row0+row)*Cc + c0];
    }
    __syncthreads();
    f32x4 aq[4], ak[4], at4[4];
    #pragma unroll
    for(int g=0;g<4;g++){ aq[g]=(f32x4){0,0,0,0}; ak[g]=(f32x4){0,0,0,0}; at4[g]=(f32x4){0,0,0,0}; }
    for(int kk=0;kk<64;kk++){
      f32x4 wq4 = *(const f32x4*)&wql[kk*64+c0];
      f32x4 wk4 = *(const f32x4*)&wkl[kk*64+c0];
      f32x4 wt4 = *(const f32x4*)&twl[kk*64+c0];
      #pragma unroll
      for(int g=0;g<4;g++){
        float xv = xr[g*16+r][kk];
        aq[g] += xv*wq4; ak[g] += xv*wk4; at4[g] += xv*wt4;
      }
    }
    float xsp[4] = {0.f,0.f,0.f,0.f};
    int q2 = c0>>4, hb = (c0>>3)&1, cs = c0&7;
    #pragma unroll
    for(int g=0;g<4;g++){
      #pragma unroll
      for(int d=0;d<4;d++) xsp[d] += xr[g*16+r][c0+d];
      long long rg = row0 + g*16 + r;
      unsigned long long hq=0,lq=0,hk=0,lk=0;
      #pragma unroll
      for(int d=0;d<4;d++){
        float v = aq[g][d];
        unsigned short h = f2bf(v); unsigned short lo2 = f2bf(v - bf2f(h));
        hq |= (unsigned long long)h << (16*d); lq |= (unsigned long long)lo2 << (16*d);
        v = ak[g][d];
        h = f2bf(v); lo2 = f2bf(v - bf2f(h));
        hk |= (unsigned long long)h << (16*d); lk |= (unsigned long long)lo2 << (16*d);
      }
      int b2 = (int)(rg>>11); int s2 = ((int)rg>>5)&63;
      int l2 = ((int)rg&31) + 32*hb;
      size_t off = qk_chunk(b2, s2, q2, l2) + cs;
      *(unsigned long long*)&Qhi[off] = hq;
      *(unsigned long long*)&Qlo[off] = lq;
      *(unsigned long long*)&Khi[off] = hk;
      *(unsigned long long*)&Klo[off] = lk;
      *(f32x4*)&xt[rg*Cc + c0] = at4[g];
    }
    __syncthreads();
    #pragma unroll
    for(int d=0;d<4;d++) atomicAdd(&xsl[c0+d], xsp[d]);
    __syncthreads();
    if(t<64) Xp[blk*64+t] = xsl[t];
  } else if(blk < 768){
    // ---------------- extract ----------------
    int n = (blk-256)*4 + (t>>6); int l = t&63;
    const float* row = A + (size_t)n*Nn;
    float mn = 1e30f;
    for(int j=l;j<Nn;j+=64) mn = fminf(mn, row[j]);
    #pragma unroll
    for(int off=32;off>=1;off>>=1) mn = fminf(mn, __shfl_xor(mn,off));
    float thr = mn*1.3f;
    int bse=0;
    for(int j0=0;j0<Nn;j0+=64){
      float v = row[j0+l];
      bool f = v>thr;
      unsigned long long m = __ballot(f);
      int pos = __popcll(m & ((1ull<<l)-1ull));
      if(f && bse+pos<CAPS){ idx[n*CAPS+bse+pos]=j0+l; val[n*CAPS+bse+pos]=v-mn; }
      bse += __popcll(m);
    }
    if(l==0){ r_[n]=mn; diagA[n]=row[n]; cnt[n] = bse<CAPS? bse : CAPS; }
  } else {
    // ---------------- WvT ----------------
    float (*tile)[65] = (float(*)[65])smem;
    int n0 = (blk-768)*64;
    for(int i=0;i<16;i++){
      int cc = i*4 + (t>>6); int nn2 = t&63;
      tile[cc][nn2] = Wv[(size_t)cc*Nn + n0 + nn2];
    }
    __syncthreads();
    for(int i=0;i<16;i++){
      int nn2 = i*4 + (t>>6); int cc = t&63;
      WvT[(size_t)(n0+nn2)*Cc + cc] = tile[cc][nn2];
    }
  }
}

// ===== zpass: Zp[jq][b][m]; block = 4 waves (wave owns m-tile), Q streamed via LDS dbuf =====
__global__ __launch_bounds__(256,2) void zpass_k(
    const unsigned short* __restrict__ Qhi, const unsigned short* __restrict__ Qlo,
    const unsigned short* __restrict__ Khi, const unsigned short* __restrict__ Klo,
    float* __restrict__ Zp){
  __shared__ uint4 stg[2][512];   // 2 x 8KB: [0:256)=Qhi s-tile, [256:512)=Qlo
  int id = blockIdx.x;
  int b = id&7; int mg = (id>>3)&15; int jq = id>>7;   // 8 x 16 x 4 = 512 blocks
  int t = threadIdx.x, w = t>>6, l = t&63;
  int mt = mg*4 + w;
  // K frags in regs (per wave)
  bf16x8 Kh[4], Kl4[4];
  #pragma unroll
  for(int q=0;q<4;q++){
    Kh[q]  = *(const bf16x8*)(Khi + qk_chunk(b, mt, q, l));
    Kl4[q] = *(const bf16x8*)(Klo + qk_chunk(b, mt, q, l));
  }
  char* wbase0 = (char*)&stg[0][0] + (t>>6)*1024;
  char* wbase1 = (char*)&stg[1][0] + (t>>6)*1024;
  // prologue stage s = jq*16
  {
    int s = jq*16;
    load_lds16(Qhi + qk_chunk(b,s,0,0) + t*8, wbase0);
    load_lds16(Qlo + qk_chunk(b,s,0,0) + t*8, wbase0 + 4096);
  }
  __syncthreads();
  float zacc = 0.f;
  for(int it=0; it<16; it++){
    int buf = it&1;
    if(it+1<16){
      int s = jq*16 + it + 1;
      char* wb = buf? wbase0 : wbase1;
      load_lds16(Qhi + qk_chunk(b,s,0,0) + t*8, wb);
      load_lds16(Qlo + qk_chunk(b,s,0,0) + t*8, wb + 4096);
    }
    f32x16 sa, sb;
    #pragma unroll
    for(int r=0;r<16;r++){ sa[r]=0.f; sb[r]=0.f; }
    #pragma unroll
    for(int q=0;q<4;q++){
      bf16x8 Qh4 = *(const bf16x8*)&stg[buf][q*64 + l];
      bf16x8 Ql4 = *(const bf16x8*)&stg[buf][256 + q*64 + l];
      sa = MFMA32(Qh4, Kh[q],  sa);   // hi·hi chain
      sb = MFMA32(Ql4, Kh[q],  sb);   // lo·hi + hi·lo chain
      sb = MFMA32(Qh4, Kl4[q], sb);
    }
    float p = 0.f;
    #pragma unroll
    for(int r=0;r<16;r++) p += __expf(sa[r]+sb[r]);
    zacc += p;
    __syncthreads();   // drains prefetch (vmcnt) + ds; next buf ready
  }
  zacc += __shfl_down(zacc, 32);
  if(l<32) Zp[((size_t)(jq*8 + b))*Nn + mt*32 + l] = zacc;
}

// ===== xzt: xzf (frag-major) = bf16(x[b,m,c] / sum_jq Zp) =====
__global__ __launch_bounds__(256) void xzt_k(const float* __restrict__ x,
    const float* __restrict__ Zp, unsigned short* __restrict__ xzf){
  __shared__ float tile[64][65];
  __shared__ float izl[64];
  int id = blockIdx.x; int b = id&7; int mt = id>>3;  // 32 m-tiles of 64
  int m0 = mt*64; int t = threadIdx.x;
  for(int i=0;i<16;i++){
    int mm = i*4 + (t>>6); int cc = t&63;
    tile[mm][cc] = x[((size_t)b*Nn + m0+mm)*Cc + cc];
  }
  if(t<64){
    float z = 0.f;
    #pragma unroll
    for(int jq=0;jq<4;jq++) z += Zp[((size_t)(jq*8 + b))*Nn + m0 + t];
    izl[t] = 1.0f/z;
  }
  __syncthreads();
  #pragma unroll
  for(int i=0;i<2;i++){
    int k2 = i*256 + t; int mg = k2>>6; int c = k2&63;
    int mloc = mg*8;
    unsigned u0 = pk2(tile[mloc+0][c]*izl[mloc+0], tile[mloc+1][c]*izl[mloc+1]);
    unsigned u1 = pk2(tile[mloc+2][c]*izl[mloc+2], tile[mloc+3][c]*izl[mloc+3]);
    unsigned u2 = pk2(tile[mloc+4][c]*izl[mloc+4], tile[mloc+5][c]*izl[mloc+5]);
    unsigned u3 = pk2(tile[mloc+6][c]*izl[mloc+6], tile[mloc+7][c]*izl[mloc+7]);
    u32x4 uu = {u0,u1,u2,u3};
    int mq = (m0 + mloc)>>4; int cb = c>>5; int l2 = (c&31) + 32*(mg&1);
    *(u32x4*)(xzf + xz_chunk(b, mq, cb, l2)) = uu;
  }
}

// ===== fused: Pp[mq][b,j,c]; block = 4 waves (wave owns j-subtile), K+xz streamed via LDS =====
__global__ __launch_bounds__(256,2) void fused_k(
    const unsigned short* __restrict__ Qhi, const unsigned short* __restrict__ Qlo,
    const unsigned short* __restrict__ Khi, const unsigned short* __restrict__ Klo,
    const unsigned short* __restrict__ xzf, float* __restrict__ Pp){
  __shared__ uint4 stg[2][768];  // 2 x 12KB: [0:256)=Khi, [256:512)=Klo, [512:768)=xz
  int id = blockIdx.x;
  int b = id&7; int jb = (id>>3)&15; int mq4 = id>>7;   // 8 x 16 x 4 = 512 blocks
  int t = threadIdx.x, w = t>>6, l = t&63, lr = l&31, hh = l>>5;
  int js = jb*4 + w;
  // hoisted Q B-frags in regs (swapped: Q is the B operand, col = j)
  bf16x8 Qh4[4], Ql4[4];
  #pragma unroll
  for(int q=0;q<4;q++){
    Qh4[q] = *(const bf16x8*)(Qhi + qk_chunk(b, js, q, l));
    Ql4[q] = *(const bf16x8*)(Qlo + qk_chunk(b, js, q, l));
  }
  char* wbase0 = (char*)&stg[0][0] + (t>>6)*1024;
  char* wbase1 = (char*)&stg[1][0] + (t>>6)*1024;
  // prologue stage s = mq4*16
  {
    int s = mq4*16;
    load_lds16(Khi + qk_chunk(b,s,0,0) + t*8, wbase0);
    load_lds16(Klo + qk_chunk(b,s,0,0) + t*8, wbase0 + 4096);
    load_lds16(xzf + xz_chunk(b,2*s,0,0) + t*8, wbase0 + 8192);
  }
  __syncthreads();
  f32x16 pa0, pa1;
  #pragma unroll
  for(int r=0;r<16;r++){ pa0[r]=0.f; pa1[r]=0.f; }
  for(int it=0; it<16; it++){
    int buf = it&1;
    if(it+1<16){
      int s = mq4*16 + it + 1;
      char* wb = buf? wbase0 : wbase1;
      load_lds16(Khi + qk_chunk(b,s,0,0) + t*8, wb);
      load_lds16(Klo + qk_chunk(b,s,0,0) + t*8, wb + 4096);
      load_lds16(xzf + xz_chunk(b,2*s,0,0) + t*8, wb + 8192);
    }
    f32x16 sa, sb;
    #pragma unroll
    for(int r=0;r<16;r++){ sa[r]=0.f; sb[r]=0.f; }
    #pragma unroll
    for(int q=0;q<4;q++){
      bf16x8 Kh4 = *(const bf16x8*)&stg[buf][q*64 + l];
      bf16x8 Kl4 = *(const bf16x8*)&stg[buf][256 + q*64 + l];
      sa = MFMA32(Kh4, Qh4[q], sa);   // hi·hi chain
      sb = MFMA32(Kl4, Qh4[q], sb);   // lo·hi + hi·lo chain
      sb = MFMA32(Kh4, Ql4[q], sb);
    }
    bf16x8 b00 = *(const bf16x8*)&stg[buf][512 + l];        // (mq,  cb0)
    bf16x8 b10 = *(const bf16x8*)&stg[buf][512 + 64 + l];   // (mq,  cb1)
    bf16x8 b01 = *(const bf16x8*)&stg[buf][512 + 128 + l];  // (mq+1,cb0)
    bf16x8 b11 = *(const bf16x8*)&stg[buf][512 + 192 + l];  // (mq+1,cb1)
    // E = bf16(exp(S)); relayout C-frag -> A-frags via permlane32_swap (T12)
    unsigned wd0,wd1,wd2,wd3,wd4,wd5,wd6,wd7;
    {
      unsigned x0 = pk2(__expf(sa[0]+sb[0]),   __expf(sa[1]+sb[1]));
      unsigned x1 = pk2(__expf(sa[2]+sb[2]),   __expf(sa[3]+sb[3]));
      unsigned y0 = pk2(__expf(sa[4]+sb[4]),   __expf(sa[5]+sb[5]));
      unsigned y1 = pk2(__expf(sa[6]+sb[6]),   __expf(sa[7]+sb[7]));
      asm("v_permlane32_swap_b32 %0, %1" : "+v"(x0), "+v"(y0));
      asm("v_permlane32_swap_b32 %0, %1" : "+v"(x1), "+v"(y1));
      wd0=x0; wd1=x1; wd2=y0; wd3=y1;
      unsigned x2 = pk2(__expf(sa[8]+sb[8]),   __expf(sa[9]+sb[9]));
      unsigned x3 = pk2(__expf(sa[10]+sb[10]), __expf(sa[11]+sb[11]));
      unsigned y2 = pk2(__expf(sa[12]+sb[12]), __expf(sa[13]+sb[13]));
      unsigned y3 = pk2(__expf(sa[14]+sb[14]), __expf(sa[15]+sb[15]));
      asm("v_permlane32_swap_b32 %0, %1" : "+v"(x2), "+v"(y2));
      asm("v_permlane32_swap_b32 %0, %1" : "+v"(x3), "+v"(y3));
      wd4=x2; wd5=x3; wd6=y2; wd7=y3;
    }
    u32x4 u1 = {wd0,wd1,wd2,wd3};
    u32x4 u2 = {wd4,wd5,wd6,wd7};
    bf16x8 f1 = __builtin_bit_cast(bf16x8, u1);   // E rows j, k = m 0..15 of tile
    bf16x8 f2 = __builtin_bit_cast(bf16x8, u2);   // E rows j, k = m 16..31
    pa0 = MFMA32(f1, b00, pa0);
    pa0 = MFMA32(f2, b01, pa0);
    pa1 = MFMA32(f1, b10, pa1);
    pa1 = MFMA32(f2, b11, pa1);
    __syncthreads();   // drains prefetch; next buf ready
  }
  // epilogue: direct store (once per block; wave owns complete rows for this m-quarter)
  float* Pb = Pp + ((size_t)(mq4*8 + b)*Nn + js*32)*Cc;
  #pragma unroll
  for(int r=0;r<16;r++){
    int jr = (r&3) + 8*(r>>2) + 4*hh;
    Pb[(size_t)jr*Cc + lr]      = pa0[r];
    Pb[(size_t)jr*Cc + 32 + lr] = pa1[r];
  }
}

// ===== psum: P = sum of 4 m-quarter partials (streaming, coalesced) =====
__global__ __launch_bounds__(256) void psum_k(const float* __restrict__ Pp,
                                              float* __restrict__ P){
  size_t i = ((size_t)blockIdx.x*256 + threadIdx.x)*4;
  const size_t st = (size_t)Bb*Nn*Cc;
  f32x4 a = *(const f32x4*)(Pp + i);
  f32x4 b = *(const f32x4*)(Pp + st + i);
  f32x4 c = *(const f32x4*)(Pp + 2*st + i);
  f32x4 d = *(const f32x4*)(Pp + 3*st + i);
  *(f32x4*)(P + i) = (a+b)+(c+d);
}

// ---------------- final: dy_diag + elementwise combine (single P gather) ----------------
__global__ __launch_bounds__(256) void final_k(const float* __restrict__ x,
    const float* __restrict__ xt, const float* __restrict__ P,
    const float* __restrict__ WvT, const float* __restrict__ Xp,
    const float* __restrict__ r_, const float* __restrict__ diagA,
    const int* __restrict__ cnt, const int* __restrict__ idx,
    const float* __restrict__ val, const float* __restrict__ tb,
    const float* __restrict__ alp, const float* __restrict__ bet,
    float* __restrict__ out){
  int t=threadIdx.x; int l=t&63;
  int bn = blockIdx.x*4 + (t>>6);
  int b = bn>>11, n = bn&2047;
  float wv = WvT[n*Cc+l];
  float xs = 0.f;
  const float* xpb = Xp + (size_t)b*32*Cc;
  #pragma unroll 8
  for(int p=0;p<32;p++) xs += xpb[p*Cc + l];
  float tacc = r_[n]*xs;
  int cn = cnt[n];
  const float* Pb = P + (size_t)b*Nn*Cc;
  const int* ix = idx + n*CAPS;
  const float* vl = val + n*CAPS;
  for(int k=0;k<cn;k++)
    tacc += vl[k] * Pb[(size_t)ix[k]*Cc + l];
  float d = wv*tacc;
  #pragma unroll
  for(int off=32;off>=1;off>>=1) d += __shfl_xor(d,off);
  size_t g = (size_t)bn*Cc + l;
  float o = alp[0]*diagA[n]*x[g] + bet[0]*(d*xt[g] + tb[l]);
  out[g] = fmaxf(o,0.f);
}

extern "C" void kernel_launch(void* const* d_in, const int* in_sizes, int n_in,
                              void* d_out, int out_size, void* d_ws, size_t ws_size,
                              hipStream_t stream){
  const float* x  = (const float*)d_in[0];
  const float* A  = (const float*)d_in[1];
  const float* Wq = (const float*)d_in[2];
  const float* Wk = (const float*)d_in[3];
  const float* Wv = (const float*)d_in[4];
  const float* Tw = (const float*)d_in[5];
  const float* tb = (const float*)d_in[6];
  const float* alp= (const float*)d_in[7];
  const float* bet= (const float*)d_in[8];
  float* out = (float*)d_out;

  char* base = (char*)d_ws; size_t off=0;
  auto al=[&](size_t sz)->void*{ void* q = base+off; off=(off+sz+255)&~(size_t)255; return q; };
  unsigned short* Qhi=(unsigned short*)al((size_t)Bb*Nn*Cc*2);
  unsigned short* Qlo=(unsigned short*)al((size_t)Bb*Nn*Cc*2);
  unsigned short* Khi=(unsigned short*)al((size_t)Bb*Nn*Cc*2);
  unsigned short* Klo=(unsigned short*)al((size_t)Bb*Nn*Cc*2);
  float* xt  =(float*)al((size_t)Bb*Nn*Cc*4);
  float* Pp  =(float*)al((size_t)4*Bb*Nn*Cc*4);  // four m-quarters, fully written by fused_k
  float* P   =(float*)al((size_t)Bb*Nn*Cc*4);    // summed by psum_k
  float* Zp  =(float*)al((size_t)4*Bb*Nn*4);     // four j-quarters, fully written by zpass_k
  float* Xp  =(float*)al((size_t)256*Cc*4);
  float* WvT =(float*)al((size_t)Nn*Cc*4);
  float* r_  =(float*)al((size_t)Nn*4);
  float* dgA =(float*)al((size_t)Nn*4);
  int*   cnt =(int*)al((size_t)Nn*4);
  int*   idx =(int*)al((size_t)Nn*CAPS*4);
  float* val =(float*)al((size_t)Nn*CAPS*4);
  unsigned short* xzf=(unsigned short*)al((size_t)Bb*Cc*Nn*2);
  (void)ws_size;

  mega_k<<<800, 256, 0, stream>>>(x, A, Wq, Wk, Tw, Wv,
      Qhi, Qlo, Khi, Klo, xt, Xp, r_, dgA, cnt, idx, val, WvT);
  zpass_k<<<512, 256, 0, stream>>>(Qhi,Qlo,Khi,Klo,Zp);
  xzt_k<<<256, 256, 0, stream>>>(x,Zp,xzf);
  fused_k<<<512, 256, 0, stream>>>(Qhi,Qlo,Khi,Klo,xzf,Pp);
  psum_k<<<(int)((size_t)Bb*Nn*Cc/4/256), 256, 0, stream>>>(Pp,P);
  final_k<<<Bb*Nn/4, 256, 0, stream>>>(x,xt,P,WvT,Xp,r_,dgA,cnt,idx,val,tb,alp,bet,out);
}